// Round 1
// baseline (789.645 us; speedup 1.0000x reference)
//
#include <hip/hip_runtime.h>
#include <math.h>

// Problem constants
#define NLOC 1600          // 40*40 local nodes
#define NGLO 100           // 10*10 global nodes
#define EDIM 256
#define NHEADS 8
#define HDIM 32

// ---------------------------------------------------------------------------
// Pool: x[B,C,40,40] -> global nodes [100][2][256] (4x4 average pool)
// ---------------------------------------------------------------------------
__global__ __launch_bounds__(256) void pool_kernel(const float* __restrict__ x,
                                                   float* __restrict__ gn) {
    int t = blockIdx.x * 256 + threadIdx.x;          // 51200 total
    if (t >= NGLO * 2 * 256) return;
    int c = t & 255;
    int b = (t >> 8) & 1;
    int n = t >> 9;                                   // 0..99
    int p = n / 10, qq = n - p * 10;
    const float* xp = x + ((size_t)(b * 256 + c)) * 1600 + (p * 4) * 40 + qq * 4;
    float s = 0.f;
#pragma unroll
    for (int dy = 0; dy < 4; ++dy)
#pragma unroll
        for (int dx = 0; dx < 4; ++dx)
            s += xp[dy * 40 + dx];
    gn[t] = s * (1.f / 16.f);
}

// ---------------------------------------------------------------------------
// Transpose x[B,C,HW] -> local nodes [1600][2][256]
// ---------------------------------------------------------------------------
__global__ __launch_bounds__(256) void nodes_kernel(const float* __restrict__ x,
                                                    float* __restrict__ nodes) {
    int t = blockIdx.x * 256 + threadIdx.x;          // 819200 total, exact
    int c = t & 255;
    int b = (t >> 8) & 1;
    int n = t >> 9;
    nodes[t] = x[((size_t)(b * 256 + c)) * 1600 + n];
}

// ---------------------------------------------------------------------------
// GEMM: C[M,256] = A[M,256] @ W^T + bias   (W is [256,256] row-major, C=A*W^T)
// grid = (ceil(M/64), 4), block = 256. 64x64 tile, 4x4 per thread, BK=16.
// ---------------------------------------------------------------------------
__global__ __launch_bounds__(256) void gemm_kernel(const float* __restrict__ A,
                                                   const float* __restrict__ W,
                                                   const float* __restrict__ bias,
                                                   float* __restrict__ C, int M) {
    __shared__ __align__(16) float As[16][64];   // [k][m]
    __shared__ __align__(16) float Ws[16][64];   // [k][n]
    int t  = threadIdx.x;
    int tx = t & 15, ty = t >> 4;
    int bm = blockIdx.x * 64, bn = blockIdx.y * 64;

    float acc[4][4];
#pragma unroll
    for (int i = 0; i < 4; ++i)
#pragma unroll
        for (int j = 0; j < 4; ++j) acc[i][j] = 0.f;

    int idx = t * 4;
    int lm  = idx >> 4;        // 0..63 (row within tile)
    int lk  = idx & 15;        // 0..12 step 4

    for (int kb = 0; kb < 256; kb += 16) {
        __syncthreads();
        {
            int row = bm + lm;
            float4 av = make_float4(0.f, 0.f, 0.f, 0.f);
            if (row < M) av = *(const float4*)(A + (size_t)row * 256 + kb + lk);
            As[lk + 0][lm] = av.x; As[lk + 1][lm] = av.y;
            As[lk + 2][lm] = av.z; As[lk + 3][lm] = av.w;
            float4 wv = *(const float4*)(W + (size_t)(bn + lm) * 256 + kb + lk);
            Ws[lk + 0][lm] = wv.x; Ws[lk + 1][lm] = wv.y;
            Ws[lk + 2][lm] = wv.z; Ws[lk + 3][lm] = wv.w;
        }
        __syncthreads();
#pragma unroll
        for (int k = 0; k < 16; ++k) {
            float4 a4 = *(const float4*)&As[k][ty * 4];
            float4 w4 = *(const float4*)&Ws[k][tx * 4];
            acc[0][0] += a4.x * w4.x; acc[0][1] += a4.x * w4.y;
            acc[0][2] += a4.x * w4.z; acc[0][3] += a4.x * w4.w;
            acc[1][0] += a4.y * w4.x; acc[1][1] += a4.y * w4.y;
            acc[1][2] += a4.y * w4.z; acc[1][3] += a4.y * w4.w;
            acc[2][0] += a4.z * w4.x; acc[2][1] += a4.z * w4.y;
            acc[2][2] += a4.z * w4.z; acc[2][3] += a4.z * w4.w;
            acc[3][0] += a4.w * w4.x; acc[3][1] += a4.w * w4.y;
            acc[3][2] += a4.w * w4.z; acc[3][3] += a4.w * w4.w;
        }
    }
    float4 bb = *(const float4*)(bias + bn + tx * 4);
#pragma unroll
    for (int i = 0; i < 4; ++i) {
        int row = bm + ty * 4 + i;
        if (row < M) {
            float4 o;
            o.x = acc[i][0] + bb.x; o.y = acc[i][1] + bb.y;
            o.z = acc[i][2] + bb.z; o.w = acc[i][3] + bb.w;
            *(float4*)(C + (size_t)row * 256 + bn + tx * 4) = o;
        }
    }
}

// ---------------------------------------------------------------------------
// GAT attention (softmax over the BATCH axis, B=2 -> per-(i,j) sigmoid).
// q,k,v: [N][2][256] with e = h*32+d. out: same layout.
// grid = (ceil(N/32), 8 heads), block = 256.
// thread -> (i_loc = t>>3, b = (t>>2)&1, d0 = (t&3)*8)
// mode 0: edges all ones (global graph).  mode 1: 40x40 grid adjacency.
// ---------------------------------------------------------------------------
__global__ __launch_bounds__(256) void gat_attn_kernel(const float* __restrict__ q,
                                                       const float* __restrict__ k,
                                                       const float* __restrict__ v,
                                                       float* __restrict__ out,
                                                       const float* __restrict__ rel,
                                                       int N, int mode) {
    __shared__ __align__(16) float ks[32][64];   // [j_loc][b*32+d]
    __shared__ __align__(16) float vs[32][64];

    int h  = blockIdx.y;
    int i0 = blockIdx.x * 32;
    int t  = threadIdx.x;
    int i_loc = t >> 3;
    int b  = (t >> 2) & 1;
    int d0 = (t & 3) * 8;
    int i  = i0 + i_loc;
    bool valid = (i < N);
    float relh = rel[h];

    size_t qoff = ((size_t)i * 2 + b) * 256 + h * 32 + d0;
    float4 qr0 = make_float4(0.f, 0.f, 0.f, 0.f), qr1 = qr0;
    if (valid) {
        qr0 = *(const float4*)(q + qoff);
        qr1 = *(const float4*)(q + qoff + 4);
    }
    int yi = 0, xi = 0;
    if (mode == 1 && valid) { yi = i / 40; xi = i - yi * 40; }

    float4 acc0 = make_float4(0.f, 0.f, 0.f, 0.f), acc1 = acc0;

    int sjl  = t >> 3;           // staging row
    int soff = (t & 7) * 8;      // staging col (0..56 step 8)
    int sb   = soff >> 5;
    int sd   = soff & 31;

    for (int j0 = 0; j0 < N; j0 += 32) {
        __syncthreads();
        {
            int jg = j0 + sjl;
            float4 z = make_float4(0.f, 0.f, 0.f, 0.f);
            float4 ka = z, kb2 = z, va = z, vb = z;
            if (jg < N) {
                size_t off = ((size_t)jg * 2 + sb) * 256 + h * 32 + sd;
                ka  = *(const float4*)(k + off);
                kb2 = *(const float4*)(k + off + 4);
                va  = *(const float4*)(v + off);
                vb  = *(const float4*)(v + off + 4);
            }
            *(float4*)&ks[sjl][soff]     = ka;
            *(float4*)&ks[sjl][soff + 4] = kb2;
            *(float4*)&vs[sjl][soff]     = va;
            *(float4*)&vs[sjl][soff + 4] = vb;
        }
        __syncthreads();
        int jmax = (N - j0) < 32 ? (N - j0) : 32;
        for (int jl = 0; jl < jmax; ++jl) {
            const float4* kp = (const float4*)&ks[jl][(b << 5) + d0];
            float4 k1 = kp[0], k2 = kp[1];
            float s = qr0.x * k1.x + qr0.y * k1.y + qr0.z * k1.z + qr0.w * k1.w
                    + qr1.x * k2.x + qr1.y * k2.y + qr1.z * k2.z + qr1.w * k2.w;
            s += __shfl_xor(s, 1);
            s += __shfl_xor(s, 2);
            s *= 0.17677669529663687f;           // 1/sqrt(32)
            if (mode == 0) {
                s += relh;                        // edges all ones
            } else {
                int j = j0 + jl;                 // loop-uniform -> scalar div
                int yj = j / 40, xj = j - yj * 40;
                int dy = yi - yj; dy = dy < 0 ? -dy : dy;
                int dx = xi - xj; dx = dx < 0 ? -dx : dx;
                s += (dy + dx == 1) ? relh : 0.f;
            }
            float s_other = __shfl_xor(s, 4);    // partner batch
            float a = 1.f / (1.f + __expf(s_other - s));
            const float4* vp = (const float4*)&vs[jl][(b << 5) + d0];
            float4 v1 = vp[0], v2 = vp[1];
            acc0.x += a * v1.x; acc0.y += a * v1.y;
            acc0.z += a * v1.z; acc0.w += a * v1.w;
            acc1.x += a * v2.x; acc1.y += a * v2.y;
            acc1.z += a * v2.z; acc1.w += a * v2.w;
        }
    }
    if (valid) {
        *(float4*)(out + qoff)     = acc0;
        *(float4*)(out + qoff + 4) = acc1;
    }
}

// ---------------------------------------------------------------------------
// Cross attention: q [1600][2][256], k/v [100][2][256] (pooled keys; the x16
// upsample multiplicity cancels in softmax). Standard softmax over 100 keys.
// grid = (400, 8), block = 256 (4 waves = 4 query rows), lane = b*32+d.
// ---------------------------------------------------------------------------
__global__ __launch_bounds__(256) void cross_attn_kernel(const float* __restrict__ q,
                                                         const float* __restrict__ kk,
                                                         const float* __restrict__ vv,
                                                         float* __restrict__ out) {
    int h = blockIdx.y;
    int t = threadIdx.x;
    int w = t >> 6;
    int i = blockIdx.x * 4 + w;        // < 1600
    int l = t & 63;
    int b = l >> 5, d = l & 31;
    size_t qoff = ((size_t)i * 2 + b) * 256 + h * 32 + d;
    float qd = q[qoff];
    float m = -1e30f, lsum = 0.f, acc = 0.f;
    for (int j = 0; j < NGLO; ++j) {
        size_t koff = ((size_t)j * 2 + b) * 256 + h * 32 + d;
        float p = qd * kk[koff];
        p += __shfl_xor(p, 1);
        p += __shfl_xor(p, 2);
        p += __shfl_xor(p, 4);
        p += __shfl_xor(p, 8);
        p += __shfl_xor(p, 16);
        float s = p * 0.17677669529663687f;
        float mn = fmaxf(m, s);
        float so = __expf(m - mn);
        float wg = __expf(s - mn);
        lsum = lsum * so + wg;
        acc  = acc  * so + wg * vv[koff];
        m = mn;
    }
    out[qoff] = acc / lsum;
}

// ---------------------------------------------------------------------------
// LayerNorm over E=256 of (P + R), row r = n*2+b.
// mode 0: out[r][c].  mode 1: out[b*256*1600 + c*1600 + n] (final BCHW write)
// ---------------------------------------------------------------------------
__global__ __launch_bounds__(256) void ln_kernel(const float* __restrict__ P,
                                                 const float* __restrict__ R,
                                                 const float* __restrict__ g,
                                                 const float* __restrict__ bb,
                                                 float* __restrict__ out, int mode) {
    int r = blockIdx.x;
    int c = threadIdx.x;
    size_t o = (size_t)r * 256 + c;
    float x = P[o] + R[o];
    float s1 = x, s2 = x * x;
#pragma unroll
    for (int off = 1; off < 64; off <<= 1) {
        s1 += __shfl_xor(s1, off);
        s2 += __shfl_xor(s2, off);
    }
    __shared__ float w1[4], w2[4];
    int wid = c >> 6;
    if ((c & 63) == 0) { w1[wid] = s1; w2[wid] = s2; }
    __syncthreads();
    s1 = w1[0] + w1[1] + w1[2] + w1[3];
    s2 = w2[0] + w2[1] + w2[2] + w2[3];
    float mean = s1 * (1.f / 256.f);
    float var  = s2 * (1.f / 256.f) - mean * mean;
    float y = (x - mean) * rsqrtf(var + 1e-5f) * g[c] + bb[c];
    if (mode == 0) {
        out[o] = y;
    } else {
        int n = r >> 1, b = r & 1;
        out[((size_t)(b * 256 + c)) * 1600 + n] = y;
    }
}

// ---------------------------------------------------------------------------
extern "C" void kernel_launch(void* const* d_in, const int* in_sizes, int n_in,
                              void* d_out, int out_size, void* d_ws, size_t ws_size,
                              hipStream_t stream) {
    const float* x        = (const float*)d_in[0];
    const float* gat_W    = (const float*)d_in[1];  // [2][4][256][256]
    const float* gat_b    = (const float*)d_in[2];  // [2][4][256]
    const float* gat_rel  = (const float*)d_in[3];  // [2][8]
    const float* cross_W  = (const float*)d_in[4];  // [4][256][256]
    const float* cross_b  = (const float*)d_in[5];  // [4][256]
    const float* ln_g     = (const float*)d_in[6];  // [3][256]
    const float* ln_b     = (const float*)d_in[7];  // [3][256]
    float* out = (float*)d_out;

    const size_t LOC = (size_t)NLOC * 2 * 256;   // 819200 floats
    const size_t GLO = (size_t)NGLO * 2 * 256;   // 51200 floats
    float* ws = (float*)d_ws;
    float* ln_nodes = ws;                 // local nodes
    float* lq    = ln_nodes + LOC;
    float* lk    = lq + LOC;
    float* lv    = lk + LOC;
    float* l_att = lv + LOC;
    float* l_out = l_att + LOC;
    float* gn    = l_out + LOC;           // global nodes
    float* gq    = gn + GLO;
    float* gk    = gq + GLO;
    float* gv    = gk + GLO;
    float* g_att = gv + GLO;
    float* g_prj = g_att + GLO;
    float* g_out = g_prj + GLO;
    float* ck    = g_out + GLO;
    float* cv    = ck + GLO;
    // reuse: l_proj = lq, cq = lk, c_att = lv, c_proj = l_att

    const float* W0 = gat_W;                   // global GAT weights [4][E][E]
    const float* W1 = gat_W + 4 * 65536;       // local GAT weights
    const float* b0 = gat_b;
    const float* b1 = gat_b + 4 * 256;

    pool_kernel <<<200, 256, 0, stream>>>(x, gn);
    nodes_kernel<<<3200, 256, 0, stream>>>(x, ln_nodes);

    // ---- global GAT ----
    gemm_kernel<<<dim3(4, 4), 256, 0, stream>>>(gn, W0 + 0 * 65536, b0 + 0, gq, 200);
    gemm_kernel<<<dim3(4, 4), 256, 0, stream>>>(gn, W0 + 1 * 65536, b0 + 256, gk, 200);
    gemm_kernel<<<dim3(4, 4), 256, 0, stream>>>(gn, W0 + 2 * 65536, b0 + 512, gv, 200);
    gat_attn_kernel<<<dim3(4, 8), 256, 0, stream>>>(gq, gk, gv, g_att, gat_rel, NGLO, 0);
    gemm_kernel<<<dim3(4, 4), 256, 0, stream>>>(g_att, W0 + 3 * 65536, b0 + 768, g_prj, 200);
    ln_kernel<<<200, 256, 0, stream>>>(g_prj, gn, ln_g, ln_b, g_out, 0);

    // ---- local GAT ----
    gemm_kernel<<<dim3(50, 4), 256, 0, stream>>>(ln_nodes, W1 + 0 * 65536, b1 + 0, lq, 3200);
    gemm_kernel<<<dim3(50, 4), 256, 0, stream>>>(ln_nodes, W1 + 1 * 65536, b1 + 256, lk, 3200);
    gemm_kernel<<<dim3(50, 4), 256, 0, stream>>>(ln_nodes, W1 + 2 * 65536, b1 + 512, lv, 3200);
    gat_attn_kernel<<<dim3(50, 8), 256, 0, stream>>>(lq, lk, lv, l_att, gat_rel + 8, NLOC, 1);
    gemm_kernel<<<dim3(50, 4), 256, 0, stream>>>(l_att, W1 + 3 * 65536, b1 + 768, lq, 3200); // l_proj = lq
    ln_kernel<<<3200, 256, 0, stream>>>(lq, ln_nodes, ln_g + 256, ln_b + 256, l_out, 0);

    // ---- cross attention (keys collapse to the 100 pooled nodes) ----
    gemm_kernel<<<dim3(50, 4), 256, 0, stream>>>(l_out, cross_W + 0 * 65536, cross_b + 0, lk, 3200); // cq = lk
    gemm_kernel<<<dim3(4, 4), 256, 0, stream>>>(g_out, cross_W + 1 * 65536, cross_b + 256, ck, 200);
    gemm_kernel<<<dim3(4, 4), 256, 0, stream>>>(g_out, cross_W + 2 * 65536, cross_b + 512, cv, 200);
    cross_attn_kernel<<<dim3(400, 8), 256, 0, stream>>>(lk, ck, cv, lv);  // c_att = lv
    gemm_kernel<<<dim3(50, 4), 256, 0, stream>>>(lv, cross_W + 3 * 65536, cross_b + 768, l_att, 3200); // c_proj = l_att
    ln_kernel<<<3200, 256, 0, stream>>>(l_att, l_out, ln_g + 512, ln_b + 512, out, 1);
}

// Round 2
// 424.294 us; speedup vs baseline: 1.8611x; 1.8611x over previous
//
#include <hip/hip_runtime.h>
#include <math.h>

#define NLOC 1600          // 40*40 local nodes
#define NGLO 100           // 10*10 global nodes

typedef unsigned short u16;
typedef short s16x8 __attribute__((ext_vector_type(8)));   // 8 bf16 (4 VGPRs)
typedef float f32x4 __attribute__((ext_vector_type(4)));   // MFMA C/D

__device__ __forceinline__ short f2bf(float f) {           // RNE f32->bf16
    unsigned u = __float_as_uint(f);
    u += 0x7fffu + ((u >> 16) & 1u);
    return (short)(u >> 16);
}
__device__ __forceinline__ float bf2f(u16 h) {
    return __uint_as_float(((unsigned)h) << 16);
}

// ---------------------------------------------------------------------------
// Pool: x[B,C,40,40] -> global nodes [100][2][256] (4x4 average pool)
// ---------------------------------------------------------------------------
__global__ __launch_bounds__(256) void pool_kernel(const float* __restrict__ x,
                                                   float* __restrict__ gn) {
    int t = blockIdx.x * 256 + threadIdx.x;
    if (t >= NGLO * 2 * 256) return;
    int c = t & 255;
    int b = (t >> 8) & 1;
    int n = t >> 9;
    int p = n / 10, qq = n - p * 10;
    const float* xp = x + ((size_t)(b * 256 + c)) * 1600 + (p * 4) * 40 + qq * 4;
    float s = 0.f;
#pragma unroll
    for (int dy = 0; dy < 4; ++dy)
#pragma unroll
        for (int dx = 0; dx < 4; ++dx)
            s += xp[dy * 40 + dx];
    gn[t] = s * (1.f / 16.f);
}

// ---------------------------------------------------------------------------
// Transpose x[B,C,HW] -> local nodes [1600][2][256]
// ---------------------------------------------------------------------------
__global__ __launch_bounds__(256) void nodes_kernel(const float* __restrict__ x,
                                                    float* __restrict__ nodes) {
    int t = blockIdx.x * 256 + threadIdx.x;
    int c = t & 255;
    int b = (t >> 8) & 1;
    int n = t >> 9;
    nodes[t] = x[((size_t)(b * 256 + c)) * 1600 + n];
}

// ---------------------------------------------------------------------------
// GEMM: C[M,256] = A[M,256] @ W^T + bias. Output fp32 or bf16 (template).
// grid = (ceil(M/64), 4), block = 256. 64x64 tile, 4x4/thread, BK=16.
// ---------------------------------------------------------------------------
template <bool BF16OUT>
__global__ __launch_bounds__(256) void gemm_kernel(const float* __restrict__ A,
                                                   const float* __restrict__ W,
                                                   const float* __restrict__ bias,
                                                   void* __restrict__ Cout, int M) {
    __shared__ __align__(16) float As[16][64];
    __shared__ __align__(16) float Ws[16][64];
    int t  = threadIdx.x;
    int tx = t & 15, ty = t >> 4;
    int bm = blockIdx.x * 64, bn = blockIdx.y * 64;

    float acc[4][4];
#pragma unroll
    for (int i = 0; i < 4; ++i)
#pragma unroll
        for (int j = 0; j < 4; ++j) acc[i][j] = 0.f;

    int idx = t * 4;
    int lm  = idx >> 4;
    int lk  = idx & 15;

    for (int kb = 0; kb < 256; kb += 16) {
        __syncthreads();
        {
            int row = bm + lm;
            float4 av = make_float4(0.f, 0.f, 0.f, 0.f);
            if (row < M) av = *(const float4*)(A + (size_t)row * 256 + kb + lk);
            As[lk + 0][lm] = av.x; As[lk + 1][lm] = av.y;
            As[lk + 2][lm] = av.z; As[lk + 3][lm] = av.w;
            float4 wv = *(const float4*)(W + (size_t)(bn + lm) * 256 + kb + lk);
            Ws[lk + 0][lm] = wv.x; Ws[lk + 1][lm] = wv.y;
            Ws[lk + 2][lm] = wv.z; Ws[lk + 3][lm] = wv.w;
        }
        __syncthreads();
#pragma unroll
        for (int k = 0; k < 16; ++k) {
            float4 a4 = *(const float4*)&As[k][ty * 4];
            float4 w4 = *(const float4*)&Ws[k][tx * 4];
            acc[0][0] += a4.x * w4.x; acc[0][1] += a4.x * w4.y;
            acc[0][2] += a4.x * w4.z; acc[0][3] += a4.x * w4.w;
            acc[1][0] += a4.y * w4.x; acc[1][1] += a4.y * w4.y;
            acc[1][2] += a4.y * w4.z; acc[1][3] += a4.y * w4.w;
            acc[2][0] += a4.z * w4.x; acc[2][1] += a4.z * w4.y;
            acc[2][2] += a4.z * w4.z; acc[2][3] += a4.z * w4.w;
            acc[3][0] += a4.w * w4.x; acc[3][1] += a4.w * w4.y;
            acc[3][2] += a4.w * w4.z; acc[3][3] += a4.w * w4.w;
        }
    }
    float4 bb = *(const float4*)(bias + bn + tx * 4);
#pragma unroll
    for (int i = 0; i < 4; ++i) {
        int row = bm + ty * 4 + i;
        if (row < M) {
            if (BF16OUT) {
                u16* Cb = (u16*)Cout;
                ushort4 o;
                o.x = (u16)f2bf(acc[i][0] + bb.x);
                o.y = (u16)f2bf(acc[i][1] + bb.y);
                o.z = (u16)f2bf(acc[i][2] + bb.z);
                o.w = (u16)f2bf(acc[i][3] + bb.w);
                *(ushort4*)(Cb + (size_t)row * 256 + bn + tx * 4) = o;
            } else {
                float* Cf = (float*)Cout;
                float4 o;
                o.x = acc[i][0] + bb.x; o.y = acc[i][1] + bb.y;
                o.z = acc[i][2] + bb.z; o.w = acc[i][3] + bb.w;
                *(float4*)(Cf + (size_t)row * 256 + bn + tx * 4) = o;
            }
        }
    }
}

// ---------------------------------------------------------------------------
// V transpose: src [M=2N][256] bf16 -> dst [2][256][Npad] bf16, zero-padded.
// dst[b][e][n] = src[2n+b][e].  grid = (Npad/16, 8), block = 256 (32x8).
// ---------------------------------------------------------------------------
__global__ __launch_bounds__(256) void vtrans_kernel(const u16* __restrict__ src,
                                                     u16* __restrict__ dst,
                                                     int M, int Npad) {
    __shared__ u16 tile[32][33];
    int m0 = blockIdx.x * 32;
    int e0 = blockIdx.y * 32;
    int tx = threadIdx.x & 31, ty = threadIdx.x >> 5;
#pragma unroll
    for (int k2 = 0; k2 < 4; ++k2) {
        int m = m0 + ty + k2 * 8;
        tile[ty + k2 * 8][tx] = (m < M) ? src[(size_t)m * 256 + e0 + tx] : (u16)0;
    }
    __syncthreads();
    int b = tx >> 4, nl = tx & 15;
    int n = (m0 >> 1) + nl;
    if (n < Npad) {
#pragma unroll
        for (int k2 = 0; k2 < 4; ++k2) {
            int e = e0 + ty + k2 * 8;
            dst[(size_t)(b * 256 + e) * Npad + n] = tile[2 * nl + b][ty + k2 * 8];
        }
    }
}

// ---------------------------------------------------------------------------
// Column-sum of V for batch 1: sumv1[e] = sum_n vt[1][e][n]
// ---------------------------------------------------------------------------
__global__ __launch_bounds__(64) void colsum_kernel(const u16* __restrict__ vt,
                                                    float* __restrict__ sumv1,
                                                    int Npad) {
    int e = blockIdx.x;
    const u16* row = vt + (size_t)(256 + e) * Npad;
    float s = 0.f;
    for (int n = threadIdx.x; n < Npad; n += 64) s += bf2f(row[n]);
#pragma unroll
    for (int off = 1; off < 64; off <<= 1) s += __shfl_xor(s, off);
    if (threadIdx.x == 0) sumv1[e] = s;
}

// ---------------------------------------------------------------------------
// GAT attention, MFMA version.
// Softmax over batch => a0 = sigmoid((q1k1 - q0k0)/sqrt32), a1 = 1-a0.
// Edge bias cancels (same for both batches). O1 = sumV1 - sum a0*V1.
// q,k: [N][2][256] bf16. vt: [2][256][Npad] bf16 (zero-padded). out fp32.
// 1 wave per block; block = (h, i-tile of 16). grid = 8*nIT.
// ---------------------------------------------------------------------------
struct KV { s16x8 kf[2][2]; s16x8 vf[2][2]; };

__global__ __launch_bounds__(64) void gat_attn_mfma(
    const u16* __restrict__ qb, const u16* __restrict__ kb,
    const u16* __restrict__ vt, const float* __restrict__ sumv1,
    float* __restrict__ out, int N, int Npad, int nIT)
{
    __shared__ short At[16][40];   // a0 tile, padded rows (80B) for 16B-aligned b128 reads
    int lane = threadIdx.x;
    int c  = lane & 15;
    int qd = lane >> 4;
    int h  = blockIdx.x / nIT;
    int it = blockIdx.x - h * nIT;
    int i0 = it * 16;
    int hb = h * 32;

    // Q A-frags: lane holds Q[i0+c][b][hb + qd*8 .. +8]
    s16x8 qf0 = {}, qf1 = {};
    int i = i0 + c;
    if (i < N) {
        const u16* qp = qb + ((size_t)i * 2) * 256 + hb + qd * 8;
        qf0 = *(const s16x8*)qp;
        qf1 = *(const s16x8*)(qp + 256);
    }
#pragma unroll
    for (int z = 0; z < 8; ++z) qf0[z] ^= (short)0x8000;   // negate b0 -> mfma gives q1k1-q0k0

    f32x4 o0[2] = {};   // O for batch 0, d-halves
    f32x4 t1[2] = {};   // T = sum a0*V1

    auto load_kv = [&](KV& B, int j0) {
#pragma unroll
        for (int b = 0; b < 2; ++b)
#pragma unroll
            for (int js = 0; js < 2; ++js) {
                int j = j0 + js * 16 + c;
                s16x8 kv = {};
                if (j < N) kv = *(const s16x8*)(kb + ((size_t)j * 2 + b) * 256 + hb + qd * 8);
                B.kf[b][js] = kv;
            }
#pragma unroll
        for (int b = 0; b < 2; ++b)
#pragma unroll
            for (int dh = 0; dh < 2; ++dh)
                B.vf[b][dh] = *(const s16x8*)(vt + (size_t)(b * 256 + hb + dh * 16 + c) * Npad
                                              + j0 + qd * 8);
    };

    auto compute = [&](KV& B) {
        f32x4 z4 = {};
        f32x4 sd0 = __builtin_amdgcn_mfma_f32_16x16x32_bf16(qf0, B.kf[0][0], z4, 0, 0, 0);
        sd0       = __builtin_amdgcn_mfma_f32_16x16x32_bf16(qf1, B.kf[1][0], sd0, 0, 0, 0);
        f32x4 sd1 = __builtin_amdgcn_mfma_f32_16x16x32_bf16(qf0, B.kf[0][1], z4, 0, 0, 0);
        sd1       = __builtin_amdgcn_mfma_f32_16x16x32_bf16(qf1, B.kf[1][1], sd1, 0, 0, 0);
        // a0 = 1/(1+exp((s1-s0)/sqrt(32))); write C-layout (row=4qd+r, col=j) to LDS
#pragma unroll
        for (int r = 0; r < 4; ++r) {
            float e0v = __expf(sd0[r] * 0.17677669529663687f);
            At[4 * qd + r][c]      = f2bf(__builtin_amdgcn_rcpf(1.f + e0v));
            float e1v = __expf(sd1[r] * 0.17677669529663687f);
            At[4 * qd + r][16 + c] = f2bf(__builtin_amdgcn_rcpf(1.f + e1v));
        }
        asm volatile("s_waitcnt lgkmcnt(0)" ::: "memory");
        // read back as A-operand frag: row c, cols qd*8..+8
        s16x8 af = *(const s16x8*)&At[c][qd * 8];
        o0[0] = __builtin_amdgcn_mfma_f32_16x16x32_bf16(af, B.vf[0][0], o0[0], 0, 0, 0);
        o0[1] = __builtin_amdgcn_mfma_f32_16x16x32_bf16(af, B.vf[0][1], o0[1], 0, 0, 0);
        t1[0] = __builtin_amdgcn_mfma_f32_16x16x32_bf16(af, B.vf[1][0], t1[0], 0, 0, 0);
        t1[1] = __builtin_amdgcn_mfma_f32_16x16x32_bf16(af, B.vf[1][1], t1[1], 0, 0, 0);
    };

    KV B0, B1;
    load_kv(B0, 0);
    for (int j0 = 0; j0 < N; j0 += 64) {
        bool h1 = (j0 + 32 < N);
        if (h1) load_kv(B1, j0 + 32);
        compute(B0);
        if (h1) {
            if (j0 + 64 < N) load_kv(B0, j0 + 64);
            compute(B1);
        }
    }

    // epilogue: O0 direct; O1 = sumV1 - T. C/D rows = 4*qd+r, cols = dh*16+c.
#pragma unroll
    for (int dh = 0; dh < 2; ++dh) {
        float sv = sumv1[hb + dh * 16 + c];
#pragma unroll
        for (int r = 0; r < 4; ++r) {
            int ii = i0 + 4 * qd + r;
            if (ii < N) {
                size_t o = ((size_t)ii * 2) * 256 + hb + dh * 16 + c;
                out[o]       = o0[dh][r];
                out[o + 256] = sv - t1[dh][r];
            }
        }
    }
}

// ---------------------------------------------------------------------------
// Cross attention: q [1600][2][256], k/v [100][2][256] fp32 (pooled keys;
// the x16 upsample multiplicity cancels in softmax). Softmax over 100 keys.
// ---------------------------------------------------------------------------
__global__ __launch_bounds__(256) void cross_attn_kernel(const float* __restrict__ q,
                                                         const float* __restrict__ kk,
                                                         const float* __restrict__ vv,
                                                         float* __restrict__ out) {
    int h = blockIdx.y;
    int t = threadIdx.x;
    int w = t >> 6;
    int i = blockIdx.x * 4 + w;
    int l = t & 63;
    int b = l >> 5, d = l & 31;
    size_t qoff = ((size_t)i * 2 + b) * 256 + h * 32 + d;
    float qd = q[qoff];
    float m = -1e30f, lsum = 0.f, acc = 0.f;
    for (int j = 0; j < NGLO; ++j) {
        size_t koff = ((size_t)j * 2 + b) * 256 + h * 32 + d;
        float p = qd * kk[koff];
        p += __shfl_xor(p, 1);
        p += __shfl_xor(p, 2);
        p += __shfl_xor(p, 4);
        p += __shfl_xor(p, 8);
        p += __shfl_xor(p, 16);
        float s = p * 0.17677669529663687f;
        float mn = fmaxf(m, s);
        float so = __expf(m - mn);
        float wg = __expf(s - mn);
        lsum = lsum * so + wg;
        acc  = acc  * so + wg * vv[koff];
        m = mn;
    }
    out[qoff] = acc / lsum;
}

// ---------------------------------------------------------------------------
// LayerNorm over E=256 of (P + R), row r = n*2+b.
// mode 0: out[r][c].  mode 1: out[b*256*1600 + c*1600 + n] (final BCHW write)
// ---------------------------------------------------------------------------
__global__ __launch_bounds__(256) void ln_kernel(const float* __restrict__ P,
                                                 const float* __restrict__ R,
                                                 const float* __restrict__ g,
                                                 const float* __restrict__ bb,
                                                 float* __restrict__ out, int mode) {
    int r = blockIdx.x;
    int c = threadIdx.x;
    size_t o = (size_t)r * 256 + c;
    float x = P[o] + R[o];
    float s1 = x, s2 = x * x;
#pragma unroll
    for (int off = 1; off < 64; off <<= 1) {
        s1 += __shfl_xor(s1, off);
        s2 += __shfl_xor(s2, off);
    }
    __shared__ float w1[4], w2[4];
    int wid = c >> 6;
    if ((c & 63) == 0) { w1[wid] = s1; w2[wid] = s2; }
    __syncthreads();
    s1 = w1[0] + w1[1] + w1[2] + w1[3];
    s2 = w2[0] + w2[1] + w2[2] + w2[3];
    float mean = s1 * (1.f / 256.f);
    float var  = s2 * (1.f / 256.f) - mean * mean;
    float y = (x - mean) * rsqrtf(var + 1e-5f) * g[c] + bb[c];
    if (mode == 0) {
        out[o] = y;
    } else {
        int n = r >> 1, b = r & 1;
        out[((size_t)(b * 256 + c)) * 1600 + n] = y;
    }
}

// ---------------------------------------------------------------------------
extern "C" void kernel_launch(void* const* d_in, const int* in_sizes, int n_in,
                              void* d_out, int out_size, void* d_ws, size_t ws_size,
                              hipStream_t stream) {
    const float* x        = (const float*)d_in[0];
    const float* gat_W    = (const float*)d_in[1];  // [2][4][256][256]
    const float* gat_b    = (const float*)d_in[2];  // [2][4][256]
    // d_in[3] = gat_rel: cancels in the batch-axis softmax -> unused
    const float* cross_W  = (const float*)d_in[4];  // [4][256][256]
    const float* cross_b  = (const float*)d_in[5];  // [4][256]
    const float* ln_g     = (const float*)d_in[6];  // [3][256]
    const float* ln_b     = (const float*)d_in[7];  // [3][256]
    float* out = (float*)d_out;

    float* ws    = (float*)d_ws;
    float* nodes = ws;                      // [1600][2][256] f32
    float* att   = ws + 819200;             // l_att -> cq -> c_proj
    float* lout  = ws + 1638400;            // local GAT output
    float* proj  = ws + 2457600;            // l_proj -> c_att
    u16* qbuf = (u16*)(ws + 3276800);       // [1600][2][256] bf16
    u16* kbuf = qbuf + 819200;
    u16* vbuf = kbuf + 819200;
    u16* vtb  = vbuf + 819200;              // [2][256][1600] bf16
    float* gn   = ws + 4915200;             // [100][2][256] f32
    float* gatt = gn   + 51200;
    float* gprj = gatt + 51200;
    float* gout = gprj + 51200;
    float* ck   = gout + 51200;
    float* cv   = ck   + 51200;
    float* sv1l = cv   + 51200;             // [256]
    float* sv1g = sv1l + 256;               // [256]
    u16* gqb = (u16*)(sv1g + 256);          // [100][2][256] bf16
    u16* gkb = gqb + 51200;
    u16* gvb = gkb + 51200;
    u16* gvt = gvb + 51200;                 // [2][256][128] bf16 (zero-padded)

    const float* W0 = gat_W;
    const float* W1 = gat_W + 4 * 65536;
    const float* b0 = gat_b;
    const float* b1 = gat_b + 4 * 256;

    pool_kernel <<<200, 256, 0, stream>>>(x, gn);
    nodes_kernel<<<3200, 256, 0, stream>>>(x, nodes);

    // ---- global GAT ----
    gemm_kernel<true><<<dim3(4, 4), 256, 0, stream>>>(gn, W0 + 0 * 65536, b0 + 0,   gqb, 200);
    gemm_kernel<true><<<dim3(4, 4), 256, 0, stream>>>(gn, W0 + 1 * 65536, b0 + 256, gkb, 200);
    gemm_kernel<true><<<dim3(4, 4), 256, 0, stream>>>(gn, W0 + 2 * 65536, b0 + 512, gvb, 200);
    vtrans_kernel<<<dim3(8, 8), 256, 0, stream>>>(gvb, gvt, 200, 128);
    colsum_kernel<<<256, 64, 0, stream>>>(gvt, sv1g, 128);
    gat_attn_mfma<<<8 * 7, 64, 0, stream>>>(gqb, gkb, gvt, sv1g, gatt, NGLO, 128, 7);
    gemm_kernel<false><<<dim3(4, 4), 256, 0, stream>>>(gatt, W0 + 3 * 65536, b0 + 768, gprj, 200);
    ln_kernel<<<200, 256, 0, stream>>>(gprj, gn, ln_g, ln_b, gout, 0);

    // ---- local GAT ----
    gemm_kernel<true><<<dim3(50, 4), 256, 0, stream>>>(nodes, W1 + 0 * 65536, b1 + 0,   qbuf, 3200);
    gemm_kernel<true><<<dim3(50, 4), 256, 0, stream>>>(nodes, W1 + 1 * 65536, b1 + 256, kbuf, 3200);
    gemm_kernel<true><<<dim3(50, 4), 256, 0, stream>>>(nodes, W1 + 2 * 65536, b1 + 512, vbuf, 3200);
    vtrans_kernel<<<dim3(100, 8), 256, 0, stream>>>(vbuf, vtb, 3200, 1600);
    colsum_kernel<<<256, 64, 0, stream>>>(vtb, sv1l, 1600);
    gat_attn_mfma<<<8 * 100, 64, 0, stream>>>(qbuf, kbuf, vtb, sv1l, att, NLOC, 1600, 100);
    gemm_kernel<false><<<dim3(50, 4), 256, 0, stream>>>(att, W1 + 3 * 65536, b1 + 768, proj, 3200);
    ln_kernel<<<3200, 256, 0, stream>>>(proj, nodes, ln_g + 256, ln_b + 256, lout, 0);

    // ---- cross attention (keys collapse to the 100 pooled nodes) ----
    gemm_kernel<false><<<dim3(50, 4), 256, 0, stream>>>(lout, cross_W + 0 * 65536, cross_b + 0, att, 3200);   // cq
    gemm_kernel<false><<<dim3(4, 4), 256, 0, stream>>>(gout, cross_W + 1 * 65536, cross_b + 256, ck, 200);
    gemm_kernel<false><<<dim3(4, 4), 256, 0, stream>>>(gout, cross_W + 2 * 65536, cross_b + 512, cv, 200);
    cross_attn_kernel<<<dim3(400, 8), 256, 0, stream>>>(att, ck, cv, proj);                                   // c_att
    gemm_kernel<false><<<dim3(50, 4), 256, 0, stream>>>(proj, cross_W + 3 * 65536, cross_b + 768, att, 3200); // c_proj
    ln_kernel<<<3200, 256, 0, stream>>>(att, lout, ln_g + 512, ln_b + 512, out, 1);
}

// Round 3
// 278.212 us; speedup vs baseline: 2.8383x; 1.5251x over previous
//
#include <hip/hip_runtime.h>
#include <math.h>

#define NLOC 1600          // 40*40 local nodes
#define NGLO 100           // 10*10 global nodes

typedef unsigned short u16;
typedef short s16x8 __attribute__((ext_vector_type(8)));   // 8 bf16 (4 VGPRs)
typedef float f32x4 __attribute__((ext_vector_type(4)));   // MFMA C/D

__device__ __forceinline__ short f2bf(float f) {           // RNE f32->bf16
    unsigned u = __float_as_uint(f);
    u += 0x7fffu + ((u >> 16) & 1u);
    return (short)(u >> 16);
}
__device__ __forceinline__ float bf2f(u16 h) {
    return __uint_as_float(((unsigned)h) << 16);
}

// ---------------------------------------------------------------------------
// Weight conversion fp32 -> bf16 (vectorized x4)
// ---------------------------------------------------------------------------
__global__ __launch_bounds__(256) void wconv_kernel(const float* __restrict__ src,
                                                    u16* __restrict__ dst, int n4) {
    int t = blockIdx.x * 256 + threadIdx.x;
    if (t < n4) {
        float4 v = ((const float4*)src)[t];
        ushort4 o;
        o.x = (u16)f2bf(v.x); o.y = (u16)f2bf(v.y);
        o.z = (u16)f2bf(v.z); o.w = (u16)f2bf(v.w);
        ((ushort4*)dst)[t] = o;
    }
}

// ---------------------------------------------------------------------------
// Pool: x[B,C,40,40] -> global nodes [100][2][256] fp32 + bf16
// ---------------------------------------------------------------------------
__global__ __launch_bounds__(256) void pool_kernel(const float* __restrict__ x,
                                                   float* __restrict__ gn,
                                                   u16* __restrict__ gnb) {
    int t = blockIdx.x * 256 + threadIdx.x;
    if (t >= NGLO * 2 * 256) return;
    int c = t & 255;
    int b = (t >> 8) & 1;
    int n = t >> 9;
    int p = n / 10, qq = n - p * 10;
    const float* xp = x + ((size_t)(b * 256 + c)) * 1600 + (p * 4) * 40 + qq * 4;
    float s = 0.f;
#pragma unroll
    for (int dy = 0; dy < 4; ++dy)
#pragma unroll
        for (int dx = 0; dx < 4; ++dx)
            s += xp[dy * 40 + dx];
    s *= (1.f / 16.f);
    gn[t] = s;
    gnb[t] = (u16)f2bf(s);
}

// ---------------------------------------------------------------------------
// Transpose x[B,C,HW] -> local nodes [1600][2][256] fp32 + bf16
// ---------------------------------------------------------------------------
__global__ __launch_bounds__(256) void nodes_kernel(const float* __restrict__ x,
                                                    float* __restrict__ nodes,
                                                    u16* __restrict__ nodesb) {
    int t = blockIdx.x * 256 + threadIdx.x;
    int c = t & 255;
    int b = (t >> 8) & 1;
    int n = t >> 9;
    float v = x[((size_t)(b * 256 + c)) * 1600 + n];
    nodes[t] = v;
    nodesb[t] = (u16)f2bf(v);
}

// ---------------------------------------------------------------------------
// MFMA GEMM: C[M,256] = A[M,256] @ W^T + bias.  A,W bf16; C fp32 or bf16.
// 1 wave per block, 64x64 tile. grid = (ceil(M/64), 4).
// A-frag: lane holds A[m0+mi*16+c][kc*32+qd*8..+8]
// W-frag (B = W^T): lane holds W[n0+ni*16+c][kc*32+qd*8..+8]
// C/D: row = mi*16+4*qd+r, col = ni*16+c   [verified layout, m89]
// ---------------------------------------------------------------------------
template <bool BF16OUT>
__global__ __launch_bounds__(64) void gemm_mfma(const u16* __restrict__ A,
                                                const u16* __restrict__ W,
                                                const float* __restrict__ bias,
                                                void* __restrict__ Cout, int M) {
    int lane = threadIdx.x;
    int c = lane & 15, qd = lane >> 4;
    int m0 = blockIdx.x * 64, n0 = blockIdx.y * 64;

    f32x4 acc[4][4] = {};
#pragma unroll 2
    for (int kc = 0; kc < 8; ++kc) {
        int ko = kc * 32 + qd * 8;
        s16x8 af[4], bf[4];
#pragma unroll
        for (int mi = 0; mi < 4; ++mi) {
            int row = m0 + mi * 16 + c;
            s16x8 z = {};
            af[mi] = (row < M) ? *(const s16x8*)(A + (size_t)row * 256 + ko) : z;
        }
#pragma unroll
        for (int ni = 0; ni < 4; ++ni)
            bf[ni] = *(const s16x8*)(W + (size_t)(n0 + ni * 16 + c) * 256 + ko);
#pragma unroll
        for (int mi = 0; mi < 4; ++mi)
#pragma unroll
            for (int ni = 0; ni < 4; ++ni)
                acc[mi][ni] = __builtin_amdgcn_mfma_f32_16x16x32_bf16(af[mi], bf[ni],
                                                                      acc[mi][ni], 0, 0, 0);
    }
#pragma unroll
    for (int mi = 0; mi < 4; ++mi) {
#pragma unroll
        for (int r = 0; r < 4; ++r) {
            int row = m0 + mi * 16 + 4 * qd + r;
            if (row < M) {
#pragma unroll
                for (int ni = 0; ni < 4; ++ni) {
                    int col = n0 + ni * 16 + c;
                    float val = acc[mi][ni][r] + bias[col];
                    if (BF16OUT)
                        ((u16*)Cout)[(size_t)row * 256 + col] = (u16)f2bf(val);
                    else
                        ((float*)Cout)[(size_t)row * 256 + col] = val;
                }
            }
        }
    }
}

// ---------------------------------------------------------------------------
// V transpose: src [M=2N][256] bf16 -> dst [2][256][Npad] bf16, zero-padded.
// ---------------------------------------------------------------------------
__global__ __launch_bounds__(256) void vtrans_kernel(const u16* __restrict__ src,
                                                     u16* __restrict__ dst,
                                                     int M, int Npad) {
    __shared__ u16 tile[32][33];
    int m0 = blockIdx.x * 32;
    int e0 = blockIdx.y * 32;
    int tx = threadIdx.x & 31, ty = threadIdx.x >> 5;
#pragma unroll
    for (int k2 = 0; k2 < 4; ++k2) {
        int m = m0 + ty + k2 * 8;
        tile[ty + k2 * 8][tx] = (m < M) ? src[(size_t)m * 256 + e0 + tx] : (u16)0;
    }
    __syncthreads();
    int b = tx >> 4, nl = tx & 15;
    int n = (m0 >> 1) + nl;
    if (n < Npad) {
#pragma unroll
        for (int k2 = 0; k2 < 4; ++k2) {
            int e = e0 + ty + k2 * 8;
            dst[(size_t)(b * 256 + e) * Npad + n] = tile[2 * nl + b][ty + k2 * 8];
        }
    }
}

// ---------------------------------------------------------------------------
// Column-sum of V for batch 1: sumv1[e] = sum_n vt[1][e][n]
// ---------------------------------------------------------------------------
__global__ __launch_bounds__(64) void colsum_kernel(const u16* __restrict__ vt,
                                                    float* __restrict__ sumv1,
                                                    int Npad) {
    int e = blockIdx.x;
    const u16* row = vt + (size_t)(256 + e) * Npad;
    float s = 0.f;
    for (int n = threadIdx.x; n < Npad; n += 64) s += bf2f(row[n]);
#pragma unroll
    for (int off = 1; off < 64; off <<= 1) s += __shfl_xor(s, off);
    if (threadIdx.x == 0) sumv1[e] = s;
}

// ---------------------------------------------------------------------------
// GAT attention, MFMA. Softmax over batch => a0 = sigmoid((q1k1-q0k0)/sqrt32).
// Edge bias cancels. O1 = sumV1 - sum a0*V1. Output bf16.
// ---------------------------------------------------------------------------
struct KV { s16x8 kf[2][2]; s16x8 vf[2][2]; };

__global__ __launch_bounds__(64) void gat_attn_mfma(
    const u16* __restrict__ qb, const u16* __restrict__ kb,
    const u16* __restrict__ vt, const float* __restrict__ sumv1,
    u16* __restrict__ out, int N, int Npad, int nIT)
{
    __shared__ short At[16][40];
    int lane = threadIdx.x;
    int c  = lane & 15;
    int qd = lane >> 4;
    int h  = blockIdx.x / nIT;
    int it = blockIdx.x - h * nIT;
    int i0 = it * 16;
    int hb = h * 32;

    s16x8 qf0 = {}, qf1 = {};
    int i = i0 + c;
    if (i < N) {
        const u16* qp = qb + ((size_t)i * 2) * 256 + hb + qd * 8;
        qf0 = *(const s16x8*)qp;
        qf1 = *(const s16x8*)(qp + 256);
    }
#pragma unroll
    for (int z = 0; z < 8; ++z) qf0[z] ^= (short)0x8000;   // negate b0 -> s1-s0

    f32x4 o0[2] = {};
    f32x4 t1[2] = {};

    auto load_kv = [&](KV& B, int j0) {
#pragma unroll
        for (int b = 0; b < 2; ++b)
#pragma unroll
            for (int js = 0; js < 2; ++js) {
                int j = j0 + js * 16 + c;
                s16x8 kv = {};
                if (j < N) kv = *(const s16x8*)(kb + ((size_t)j * 2 + b) * 256 + hb + qd * 8);
                B.kf[b][js] = kv;
            }
#pragma unroll
        for (int b = 0; b < 2; ++b)
#pragma unroll
            for (int dh = 0; dh < 2; ++dh)
                B.vf[b][dh] = *(const s16x8*)(vt + (size_t)(b * 256 + hb + dh * 16 + c) * Npad
                                              + j0 + qd * 8);
    };

    auto compute = [&](KV& B) {
        f32x4 z4 = {};
        f32x4 sd0 = __builtin_amdgcn_mfma_f32_16x16x32_bf16(qf0, B.kf[0][0], z4, 0, 0, 0);
        sd0       = __builtin_amdgcn_mfma_f32_16x16x32_bf16(qf1, B.kf[1][0], sd0, 0, 0, 0);
        f32x4 sd1 = __builtin_amdgcn_mfma_f32_16x16x32_bf16(qf0, B.kf[0][1], z4, 0, 0, 0);
        sd1       = __builtin_amdgcn_mfma_f32_16x16x32_bf16(qf1, B.kf[1][1], sd1, 0, 0, 0);
#pragma unroll
        for (int r = 0; r < 4; ++r) {
            float e0v = __expf(sd0[r] * 0.17677669529663687f);
            At[4 * qd + r][c]      = f2bf(__builtin_amdgcn_rcpf(1.f + e0v));
            float e1v = __expf(sd1[r] * 0.17677669529663687f);
            At[4 * qd + r][16 + c] = f2bf(__builtin_amdgcn_rcpf(1.f + e1v));
        }
        asm volatile("s_waitcnt lgkmcnt(0)" ::: "memory");
        s16x8 af = *(const s16x8*)&At[c][qd * 8];
        o0[0] = __builtin_amdgcn_mfma_f32_16x16x32_bf16(af, B.vf[0][0], o0[0], 0, 0, 0);
        o0[1] = __builtin_amdgcn_mfma_f32_16x16x32_bf16(af, B.vf[0][1], o0[1], 0, 0, 0);
        t1[0] = __builtin_amdgcn_mfma_f32_16x16x32_bf16(af, B.vf[1][0], t1[0], 0, 0, 0);
        t1[1] = __builtin_amdgcn_mfma_f32_16x16x32_bf16(af, B.vf[1][1], t1[1], 0, 0, 0);
    };

    KV B0, B1;
    load_kv(B0, 0);
    for (int j0 = 0; j0 < N; j0 += 64) {
        bool h1 = (j0 + 32 < N);
        if (h1) load_kv(B1, j0 + 32);
        compute(B0);
        if (h1) {
            if (j0 + 64 < N) load_kv(B0, j0 + 64);
            compute(B1);
        }
    }

#pragma unroll
    for (int dh = 0; dh < 2; ++dh) {
        float sv = sumv1[hb + dh * 16 + c];
#pragma unroll
        for (int r = 0; r < 4; ++r) {
            int ii = i0 + 4 * qd + r;
            if (ii < N) {
                size_t o = ((size_t)ii * 2) * 256 + hb + dh * 16 + c;
                out[o]       = (u16)f2bf(o0[dh][r]);
                out[o + 256] = (u16)f2bf(sv - t1[dh][r]);
            }
        }
    }
}

// ---------------------------------------------------------------------------
// Cross attention, MFMA. q [1600][2][256] bf16; k [100][2][256] bf16;
// vt [2][256][128] bf16 zero-padded. Softmax over 100 keys (pad masked).
// 1 wave per (16-q tile, head, batch): grid = 100*16 = 1600 blocks.
// ---------------------------------------------------------------------------
__global__ __launch_bounds__(64) void cross_attn_mfma(
    const u16* __restrict__ qb, const u16* __restrict__ kb,
    const u16* __restrict__ vt, u16* __restrict__ out)
{
    __shared__ short At[16][136];   // P tile [q][j], 272B rows (16B aligned)
    int lane = threadIdx.x;
    int c  = lane & 15;
    int qd = lane >> 4;
    int bx = blockIdx.x;
    int it = bx % 100;
    int hb2 = bx / 100;
    int h = hb2 >> 1, b = hb2 & 1;
    int i0 = it * 16;
    int hb = h * 32;

    // zero the padded P columns (112..135)
    for (int z = lane; z < 16 * 24; z += 64)
        At[z / 24][112 + (z % 24)] = 0;

    // Q A-frag
    const u16* qp = qb + ((size_t)(i0 + c) * 2 + b) * 256 + hb + qd * 8;
    s16x8 qf = *(const s16x8*)qp;

    // S = Q K^T over 7 key tiles (112 padded keys)
    f32x4 s[7];
#pragma unroll
    for (int jt = 0; jt < 7; ++jt) {
        int j = jt * 16 + c;
        s16x8 kf = {};
        if (j < NGLO) kf = *(const s16x8*)(kb + ((size_t)j * 2 + b) * 256 + hb + qd * 8);
        f32x4 z4 = {};
        s[jt] = __builtin_amdgcn_mfma_f32_16x16x32_bf16(qf, kf, z4, 0, 0, 0);
    }
    // mask padded keys (tile 6, c>=4 -> j>=100)
    if (c >= 4) {
#pragma unroll
        for (int r = 0; r < 4; ++r) s[6][r] = -1e30f;
    }
    // scale
#pragma unroll
    for (int jt = 0; jt < 7; ++jt)
#pragma unroll
        for (int r = 0; r < 4; ++r) s[jt][r] *= 0.17677669529663687f;

    // row softmax (row = 4*qd+r spans the 16 c-lanes x 7 tiles)
    float l[4];
#pragma unroll
    for (int r = 0; r < 4; ++r) {
        float mm = s[0][r];
#pragma unroll
        for (int jt = 1; jt < 7; ++jt) mm = fmaxf(mm, s[jt][r]);
        mm = fmaxf(mm, __shfl_xor(mm, 1));
        mm = fmaxf(mm, __shfl_xor(mm, 2));
        mm = fmaxf(mm, __shfl_xor(mm, 4));
        mm = fmaxf(mm, __shfl_xor(mm, 8));
        float ll = 0.f;
#pragma unroll
        for (int jt = 0; jt < 7; ++jt) {
            float p = __expf(s[jt][r] - mm);
            s[jt][r] = p;
            ll += p;
        }
        ll += __shfl_xor(ll, 1);
        ll += __shfl_xor(ll, 2);
        ll += __shfl_xor(ll, 4);
        ll += __shfl_xor(ll, 8);
        l[r] = ll;
    }
    // P -> LDS (C-layout write: row 4qd+r, col jt*16+c)
#pragma unroll
    for (int jt = 0; jt < 7; ++jt)
#pragma unroll
        for (int r = 0; r < 4; ++r)
            At[4 * qd + r][jt * 16 + c] = f2bf(s[jt][r]);
    asm volatile("s_waitcnt lgkmcnt(0)" ::: "memory");

    // O = P V : 4 chunks of 32 keys x 2 d-halves
    f32x4 o[2] = {};
#pragma unroll
    for (int kc = 0; kc < 4; ++kc) {
        s16x8 af = *(const s16x8*)&At[c][kc * 32 + qd * 8];
#pragma unroll
        for (int dh = 0; dh < 2; ++dh) {
            s16x8 vf = *(const s16x8*)(vt + (size_t)(b * 256 + hb + dh * 16 + c) * 128
                                       + kc * 32 + qd * 8);
            o[dh] = __builtin_amdgcn_mfma_f32_16x16x32_bf16(af, vf, o[dh], 0, 0, 0);
        }
    }
    // epilogue: out[i][b][hb+dh*16+c] = o/l
#pragma unroll
    for (int dh = 0; dh < 2; ++dh)
#pragma unroll
        for (int r = 0; r < 4; ++r) {
            int ii = i0 + 4 * qd + r;
            out[((size_t)ii * 2 + b) * 256 + hb + dh * 16 + c] = (u16)f2bf(o[dh][r] / l[r]);
        }
}

// ---------------------------------------------------------------------------
// LayerNorm over E=256 of (P + R). fp32 out + optional bf16 shadow.
// mode 0: out[r][c].  mode 1: out[b*256*1600 + c*1600 + n] (final BCHW write)
// ---------------------------------------------------------------------------
__global__ __launch_bounds__(256) void ln_kernel(const float* __restrict__ P,
                                                 const float* __restrict__ R,
                                                 const float* __restrict__ g,
                                                 const float* __restrict__ bb,
                                                 float* __restrict__ out,
                                                 u16* __restrict__ outb, int mode) {
    int r = blockIdx.x;
    int c = threadIdx.x;
    size_t o = (size_t)r * 256 + c;
    float x = P[o] + R[o];
    float s1 = x, s2 = x * x;
#pragma unroll
    for (int off = 1; off < 64; off <<= 1) {
        s1 += __shfl_xor(s1, off);
        s2 += __shfl_xor(s2, off);
    }
    __shared__ float w1[4], w2[4];
    int wid = c >> 6;
    if ((c & 63) == 0) { w1[wid] = s1; w2[wid] = s2; }
    __syncthreads();
    s1 = w1[0] + w1[1] + w1[2] + w1[3];
    s2 = w2[0] + w2[1] + w2[2] + w2[3];
    float mean = s1 * (1.f / 256.f);
    float var  = s2 * (1.f / 256.f) - mean * mean;
    float y = (x - mean) * rsqrtf(var + 1e-5f) * g[c] + bb[c];
    if (mode == 0) {
        out[o] = y;
        if (outb) outb[o] = (u16)f2bf(y);
    } else {
        int n = r >> 1, b = r & 1;
        out[((size_t)(b * 256 + c)) * 1600 + n] = y;
    }
}

// ---------------------------------------------------------------------------
extern "C" void kernel_launch(void* const* d_in, const int* in_sizes, int n_in,
                              void* d_out, int out_size, void* d_ws, size_t ws_size,
                              hipStream_t stream) {
    const float* x        = (const float*)d_in[0];
    const float* gat_W    = (const float*)d_in[1];  // [2][4][256][256]
    const float* gat_b    = (const float*)d_in[2];  // [2][4][256]
    // d_in[3] = gat_rel: cancels in the batch-axis softmax -> unused
    const float* cross_W  = (const float*)d_in[4];  // [4][256][256]
    const float* cross_b  = (const float*)d_in[5];  // [4][256]
    const float* ln_g     = (const float*)d_in[6];  // [3][256]
    const float* ln_b     = (const float*)d_in[7];  // [3][256]
    float* out = (float*)d_out;

    float* ws    = (float*)d_ws;
    float* nodes = ws;                      // [1600][2][256] f32
    float* lout  = nodes + 819200;          // local GAT output f32
    float* proj  = lout  + 819200;          // l_proj -> c_proj f32
    float* gn    = proj  + 819200;          // [100][2][256] f32
    float* gprj  = gn    + 51200;
    float* gout  = gprj  + 51200;
    float* sv1l  = gout  + 51200;           // [256]
    float* sv1g  = sv1l  + 256;             // [256]
    u16* wgatb  = (u16*)(sv1g + 256);       // 2*4*65536 bf16 weights
    u16* wcrsb  = wgatb + 524288;           // 4*65536
    u16* nodesb = wcrsb + 262144;           // [1600][2][256] bf16
    u16* qbuf   = nodesb + 819200;
    u16* kbuf   = qbuf + 819200;            // local K; later reused as cattb
    u16* vbuf   = kbuf + 819200;            // local V; later reused as loutb
    u16* vtb    = vbuf + 819200;            // [2][256][1600]
    u16* attb   = vtb + 819200;             // l_att; later reused as cqb
    u16* gnb    = attb + 819200;            // [100][2][256]
    u16* gqb    = gnb + 51200;
    u16* gkb    = gqb + 51200;
    u16* gvb    = gkb + 51200;
    u16* gvt    = gvb + 51200;              // [2][256][128]
    u16* gattb  = gvt + 65536;
    u16* goutb  = gattb + 51200;
    u16* ckb    = goutb + 51200;
    u16* cvb    = ckb + 51200;
    u16* cvt    = cvb + 51200;              // [2][256][128]
    u16* loutb  = vbuf;                     // reuse (V consumed by vtrans)
    u16* cqb    = attb;                     // reuse (att consumed by proj gemm)
    u16* cattb  = kbuf;                     // reuse (K consumed by gat_attn)

    const u16* W0b = wgatb;                 // global GAT weights bf16
    const u16* W1b = wgatb + 4 * 65536;     // local GAT weights bf16
    const float* b0 = gat_b;
    const float* b1 = gat_b + 4 * 256;

    wconv_kernel<<<512, 256, 0, stream>>>(gat_W,   wgatb, 131072);
    wconv_kernel<<<256, 256, 0, stream>>>(cross_W, wcrsb, 65536);
    pool_kernel <<<200, 256, 0, stream>>>(x, gn, gnb);
    nodes_kernel<<<3200, 256, 0, stream>>>(x, nodes, nodesb);

    // ---- global GAT ----
    gemm_mfma<true><<<dim3(4, 4), 64, 0, stream>>>(gnb, W0b + 0 * 65536, b0 + 0,   gqb, 200);
    gemm_mfma<true><<<dim3(4, 4), 64, 0, stream>>>(gnb, W0b + 1 * 65536, b0 + 256, gkb, 200);
    gemm_mfma<true><<<dim3(4, 4), 64, 0, stream>>>(gnb, W0b + 2 * 65536, b0 + 512, gvb, 200);
    vtrans_kernel<<<dim3(8, 8), 256, 0, stream>>>(gvb, gvt, 200, 128);
    colsum_kernel<<<256, 64, 0, stream>>>(gvt, sv1g, 128);
    gat_attn_mfma<<<8 * 7, 64, 0, stream>>>(gqb, gkb, gvt, sv1g, gattb, NGLO, 128, 7);
    gemm_mfma<false><<<dim3(4, 4), 64, 0, stream>>>(gattb, W0b + 3 * 65536, b0 + 768, gprj, 200);
    ln_kernel<<<200, 256, 0, stream>>>(gprj, gn, ln_g, ln_b, gout, goutb, 0);

    // ---- local GAT ----
    gemm_mfma<true><<<dim3(50, 4), 64, 0, stream>>>(nodesb, W1b + 0 * 65536, b1 + 0,   qbuf, 3200);
    gemm_mfma<true><<<dim3(50, 4), 64, 0, stream>>>(nodesb, W1b + 1 * 65536, b1 + 256, kbuf, 3200);
    gemm_mfma<true><<<dim3(50, 4), 64, 0, stream>>>(nodesb, W1b + 2 * 65536, b1 + 512, vbuf, 3200);
    vtrans_kernel<<<dim3(100, 8), 256, 0, stream>>>(vbuf, vtb, 3200, 1600);
    colsum_kernel<<<256, 64, 0, stream>>>(vtb, sv1l, 1600);
    gat_attn_mfma<<<8 * 100, 64, 0, stream>>>(qbuf, kbuf, vtb, sv1l, attb, NLOC, 1600, 100);
    gemm_mfma<false><<<dim3(50, 4), 64, 0, stream>>>(attb, W1b + 3 * 65536, b1 + 768, proj, 3200);
    ln_kernel<<<3200, 256, 0, stream>>>(proj, nodes, ln_g + 256, ln_b + 256, lout, loutb, 0);

    // ---- cross attention (keys collapse to the 100 pooled nodes) ----
    gemm_mfma<true><<<dim3(50, 4), 64, 0, stream>>>(loutb, wcrsb + 0 * 65536, cross_b + 0, cqb, 3200);
    gemm_mfma<true><<<dim3(4, 4), 64, 0, stream>>>(goutb, wcrsb + 1 * 65536, cross_b + 256, ckb, 200);
    gemm_mfma<true><<<dim3(4, 4), 64, 0, stream>>>(goutb, wcrsb + 2 * 65536, cross_b + 512, cvb, 200);
    vtrans_kernel<<<dim3(8, 8), 256, 0, stream>>>(cvb, cvt, 200, 128);
    cross_attn_mfma<<<1600, 64, 0, stream>>>(cqb, ckb, cvt, cattb);
    gemm_mfma<false><<<dim3(50, 4), 64, 0, stream>>>(cattb, wcrsb + 3 * 65536, cross_b + 768, proj, 3200);
    ln_kernel<<<3200, 256, 0, stream>>>(proj, lout, ln_g + 512, ln_b + 512, out, (u16*)0, 1);
}

// Round 4
// 201.491 us; speedup vs baseline: 3.9190x; 1.3808x over previous
//
#include <hip/hip_runtime.h>
#include <math.h>

#define NLOC 1600          // 40*40 local nodes
#define NGLO 100           // 10*10 global nodes

typedef unsigned short u16;
typedef short s16x8 __attribute__((ext_vector_type(8)));   // 8 bf16 (4 VGPRs)
typedef float f32x4 __attribute__((ext_vector_type(4)));   // MFMA C/D

__device__ __forceinline__ short f2bf(float f) {           // RNE f32->bf16
    unsigned u = __float_as_uint(f);
    u += 0x7fffu + ((u >> 16) & 1u);
    return (short)(u >> 16);
}
__device__ __forceinline__ float bf2f(u16 h) {
    return __uint_as_float(((unsigned)h) << 16);
}

// ---------------------------------------------------------------------------
// Fused weight conversion fp32 -> bf16 (gat_W 131072 x4 + cross_W 65536 x4)
// ---------------------------------------------------------------------------
__global__ __launch_bounds__(256) void wconv_kernel(const float* __restrict__ w1,
                                                    const float* __restrict__ w2,
                                                    u16* __restrict__ d1,
                                                    u16* __restrict__ d2) {
    int t = blockIdx.x * 256 + threadIdx.x;    // 0..196607
    const float* src; u16* dst; int idx;
    if (t < 131072) { src = w1; dst = d1; idx = t; }
    else            { src = w2; dst = d2; idx = t - 131072; }
    float4 v = ((const float4*)src)[idx];
    ushort4 o;
    o.x = (u16)f2bf(v.x); o.y = (u16)f2bf(v.y);
    o.z = (u16)f2bf(v.z); o.w = (u16)f2bf(v.w);
    ((ushort4*)dst)[idx] = o;
}

// ---------------------------------------------------------------------------
// Fused prep: blocks 0..3199 transpose x -> local nodes [1600][2][256];
// blocks 3200..3399: 4x4 avg-pool -> global nodes [100][2][256]. f32 + bf16.
// ---------------------------------------------------------------------------
__global__ __launch_bounds__(256) void prep_kernel(const float* __restrict__ x,
                                                   float* __restrict__ nodes,
                                                   u16* __restrict__ nodesb,
                                                   float* __restrict__ gn,
                                                   u16* __restrict__ gnb) {
    int bid = blockIdx.x;
    if (bid < 3200) {
        int t = bid * 256 + threadIdx.x;
        int c = t & 255;
        int b = (t >> 8) & 1;
        int n = t >> 9;
        float v = x[((size_t)(b * 256 + c)) * 1600 + n];
        nodes[t] = v;
        nodesb[t] = (u16)f2bf(v);
    } else {
        int t = (bid - 3200) * 256 + threadIdx.x;
        int c = t & 255;
        int b = (t >> 8) & 1;
        int n = t >> 9;
        int p = n / 10, qq = n - p * 10;
        const float* xp = x + ((size_t)(b * 256 + c)) * 1600 + (p * 4) * 40 + qq * 4;
        float s = 0.f;
#pragma unroll
        for (int dy = 0; dy < 4; ++dy)
#pragma unroll
            for (int dx = 0; dx < 4; ++dx)
                s += xp[dy * 40 + dx];
        s *= (1.f / 16.f);
        gn[t] = s;
        gnb[t] = (u16)f2bf(s);
    }
}

// ---------------------------------------------------------------------------
// MFMA GEMM: C[M,256] = A[M,256] @ W^T + bias.  A,W bf16; C fp32 or bf16.
// 1 wave per block, 32x64 tile. grid = (ceil(M/32), 4, nz).
// z batches weight matrices: W += z*65536, bias += z*256, C += z*M*256.
// ---------------------------------------------------------------------------
template <bool BF16OUT>
__global__ __launch_bounds__(64) void gemm_mfma(const u16* __restrict__ A,
                                                const u16* __restrict__ W,
                                                const float* __restrict__ bias,
                                                void* __restrict__ Cout, int M) {
    int z = blockIdx.z;
    W    += (size_t)z * 65536;
    bias += (size_t)z * 256;
    int lane = threadIdx.x;
    int c = lane & 15, qd = lane >> 4;
    int m0 = blockIdx.x * 32, n0 = blockIdx.y * 64;
    size_t co = (size_t)z * M * 256;

    f32x4 acc[2][4] = {};
#pragma unroll 2
    for (int kc = 0; kc < 8; ++kc) {
        int ko = kc * 32 + qd * 8;
        s16x8 af[2], bf[4];
#pragma unroll
        for (int mi = 0; mi < 2; ++mi) {
            int row = m0 + mi * 16 + c;
            s16x8 zz = {};
            af[mi] = (row < M) ? *(const s16x8*)(A + (size_t)row * 256 + ko) : zz;
        }
#pragma unroll
        for (int ni = 0; ni < 4; ++ni)
            bf[ni] = *(const s16x8*)(W + (size_t)(n0 + ni * 16 + c) * 256 + ko);
#pragma unroll
        for (int mi = 0; mi < 2; ++mi)
#pragma unroll
            for (int ni = 0; ni < 4; ++ni)
                acc[mi][ni] = __builtin_amdgcn_mfma_f32_16x16x32_bf16(af[mi], bf[ni],
                                                                      acc[mi][ni], 0, 0, 0);
    }
#pragma unroll
    for (int mi = 0; mi < 2; ++mi) {
#pragma unroll
        for (int r = 0; r < 4; ++r) {
            int row = m0 + mi * 16 + 4 * qd + r;
            if (row < M) {
#pragma unroll
                for (int ni = 0; ni < 4; ++ni) {
                    int col = n0 + ni * 16 + c;
                    float val = acc[mi][ni][r] + bias[col];
                    if (BF16OUT)
                        ((u16*)Cout)[co + (size_t)row * 256 + col] = (u16)f2bf(val);
                    else
                        ((float*)Cout)[co + (size_t)row * 256 + col] = val;
                }
            }
        }
    }
}

// ---------------------------------------------------------------------------
// V transpose: src [M=2N][256] bf16 -> dst [2][256][Npad] bf16, zero-padded.
// ---------------------------------------------------------------------------
__global__ __launch_bounds__(256) void vtrans_kernel(const u16* __restrict__ src,
                                                     u16* __restrict__ dst,
                                                     int M, int Npad) {
    __shared__ u16 tile[32][33];
    int m0 = blockIdx.x * 32;
    int e0 = blockIdx.y * 32;
    int tx = threadIdx.x & 31, ty = threadIdx.x >> 5;
#pragma unroll
    for (int k2 = 0; k2 < 4; ++k2) {
        int m = m0 + ty + k2 * 8;
        tile[ty + k2 * 8][tx] = (m < M) ? src[(size_t)m * 256 + e0 + tx] : (u16)0;
    }
    __syncthreads();
    int b = tx >> 4, nl = tx & 15;
    int n = (m0 >> 1) + nl;
    if (n < Npad) {
#pragma unroll
        for (int k2 = 0; k2 < 4; ++k2) {
            int e = e0 + ty + k2 * 8;
            dst[(size_t)(b * 256 + e) * Npad + n] = tile[2 * nl + b][ty + k2 * 8];
        }
    }
}

// ---------------------------------------------------------------------------
// Column-sum of V for batch 1: sumv1[e] = sum_n vt[1][e][n]
// ---------------------------------------------------------------------------
__global__ __launch_bounds__(64) void colsum_kernel(const u16* __restrict__ vt,
                                                    float* __restrict__ sumv1,
                                                    int Npad) {
    int e = blockIdx.x;
    const u16* row = vt + (size_t)(256 + e) * Npad;
    float s = 0.f;
    for (int n = threadIdx.x; n < Npad; n += 64) s += bf2f(row[n]);
#pragma unroll
    for (int off = 1; off < 64; off <<= 1) s += __shfl_xor(s, off);
    if (threadIdx.x == 0) sumv1[e] = s;
}

// ---------------------------------------------------------------------------
// Global-graph GAT attention (small: N=100). Single-wave blocks, direct out.
// a0 = sigmoid((q1k1-q0k0)/sqrt32); edge bias cancels; O1 = sumV1 - sum a0*V1.
// ---------------------------------------------------------------------------
struct KV { s16x8 kf[2][2]; s16x8 vf[2][2]; };

__global__ __launch_bounds__(64) void gat_attn_mfma(
    const u16* __restrict__ qb, const u16* __restrict__ kb,
    const u16* __restrict__ vt, const float* __restrict__ sumv1,
    u16* __restrict__ out, int N, int Npad, int nIT)
{
    __shared__ short At[16][40];
    int lane = threadIdx.x;
    int c  = lane & 15;
    int qd = lane >> 4;
    int h  = blockIdx.x / nIT;
    int it = blockIdx.x - h * nIT;
    int i0 = it * 16;
    int hb = h * 32;

    s16x8 qf0 = {}, qf1 = {};
    int i = i0 + c;
    if (i < N) {
        const u16* qp = qb + ((size_t)i * 2) * 256 + hb + qd * 8;
        qf0 = *(const s16x8*)qp;
        qf1 = *(const s16x8*)(qp + 256);
    }
#pragma unroll
    for (int z = 0; z < 8; ++z) qf0[z] ^= (short)0x8000;   // negate b0 -> s1-s0

    f32x4 o0[2] = {};
    f32x4 t1[2] = {};

    auto load_kv = [&](KV& B, int j0) {
#pragma unroll
        for (int b = 0; b < 2; ++b)
#pragma unroll
            for (int js = 0; js < 2; ++js) {
                int j = j0 + js * 16 + c;
                s16x8 kv = {};
                if (j < N) kv = *(const s16x8*)(kb + ((size_t)j * 2 + b) * 256 + hb + qd * 8);
                B.kf[b][js] = kv;
            }
#pragma unroll
        for (int b = 0; b < 2; ++b)
#pragma unroll
            for (int dh = 0; dh < 2; ++dh)
                B.vf[b][dh] = *(const s16x8*)(vt + (size_t)(b * 256 + hb + dh * 16 + c) * Npad
                                              + j0 + qd * 8);
    };

    auto compute = [&](KV& B) {
        f32x4 z4 = {};
        f32x4 sd0 = __builtin_amdgcn_mfma_f32_16x16x32_bf16(qf0, B.kf[0][0], z4, 0, 0, 0);
        sd0       = __builtin_amdgcn_mfma_f32_16x16x32_bf16(qf1, B.kf[1][0], sd0, 0, 0, 0);
        f32x4 sd1 = __builtin_amdgcn_mfma_f32_16x16x32_bf16(qf0, B.kf[0][1], z4, 0, 0, 0);
        sd1       = __builtin_amdgcn_mfma_f32_16x16x32_bf16(qf1, B.kf[1][1], sd1, 0, 0, 0);
#pragma unroll
        for (int r = 0; r < 4; ++r) {
            float e0v = __expf(sd0[r] * 0.17677669529663687f);
            At[4 * qd + r][c]      = f2bf(__builtin_amdgcn_rcpf(1.f + e0v));
            float e1v = __expf(sd1[r] * 0.17677669529663687f);
            At[4 * qd + r][16 + c] = f2bf(__builtin_amdgcn_rcpf(1.f + e1v));
        }
        asm volatile("s_waitcnt lgkmcnt(0)" ::: "memory");
        s16x8 af = *(const s16x8*)&At[c][qd * 8];
        o0[0] = __builtin_amdgcn_mfma_f32_16x16x32_bf16(af, B.vf[0][0], o0[0], 0, 0, 0);
        o0[1] = __builtin_amdgcn_mfma_f32_16x16x32_bf16(af, B.vf[0][1], o0[1], 0, 0, 0);
        t1[0] = __builtin_amdgcn_mfma_f32_16x16x32_bf16(af, B.vf[1][0], t1[0], 0, 0, 0);
        t1[1] = __builtin_amdgcn_mfma_f32_16x16x32_bf16(af, B.vf[1][1], t1[1], 0, 0, 0);
    };

    KV B0, B1;
    load_kv(B0, 0);
    for (int j0 = 0; j0 < N; j0 += 64) {
        bool h1 = (j0 + 32 < N);
        if (h1) load_kv(B1, j0 + 32);
        compute(B0);
        if (h1) {
            if (j0 + 64 < N) load_kv(B0, j0 + 64);
            compute(B1);
        }
    }

#pragma unroll
    for (int dh = 0; dh < 2; ++dh) {
        float sv = sumv1[hb + dh * 16 + c];
#pragma unroll
        for (int r = 0; r < 4; ++r) {
            int ii = i0 + 4 * qd + r;
            if (ii < N) {
                size_t o = ((size_t)ii * 2) * 256 + hb + dh * 16 + c;
                out[o]       = (u16)f2bf(o0[dh][r]);
                out[o + 256] = (u16)f2bf(sv - t1[dh][r]);
            }
        }
    }
}

// ---------------------------------------------------------------------------
// Local GAT attention, 4-wave blocks + LDS-staged coalesced K/V + j-split.
// grid.x = ((h*25 + ic)*4 + q4), 800 blocks, 256 threads.
// Wave w handles i-tile i0 = ic*64 + w*16. j-quarter q4: j-blocks 13/13/13/11.
// Writes fp32 partials pO (= sum a0*V0) and pT (= sum a0*V1) per quarter.
// ---------------------------------------------------------------------------
__global__ __launch_bounds__(256) void lgat_attn(
    const u16* __restrict__ qb, const u16* __restrict__ kb,
    const u16* __restrict__ vt, float* __restrict__ pO, float* __restrict__ pT)
{
    __shared__ u16 ks[2][32][40];   // [b][jl][d] pad->40
    __shared__ u16 vs[2][32][40];   // [b][d][jl] pad->40
    __shared__ short At[4][16][40]; // per-wave P tile

    int tid = threadIdx.x;
    int w = tid >> 6, lane = tid & 63;
    int c = lane & 15, qd = lane >> 4;
    int bx = blockIdx.x;
    int q4 = bx & 3;
    int hic = bx >> 2;
    int ic = hic % 25, h = hic / 25;
    int hb = h * 32;
    int i0 = ic * 64 + w * 16;
    int jb0 = q4 * 13, jbe = (jb0 + 13 < 50) ? jb0 + 13 : 50;

    // Q A-frags (N=1600 divisible: no bounds checks)
    const u16* qp = qb + ((size_t)(i0 + c) * 2) * 256 + hb + qd * 8;
    s16x8 qf0 = *(const s16x8*)qp;
    s16x8 qf1 = *(const s16x8*)(qp + 256);
#pragma unroll
    for (int z = 0; z < 8; ++z) qf0[z] ^= (short)0x8000;   // negate b0 -> s1-s0

    f32x4 o0[2] = {}, t1[2] = {};

    // staging role
    int srow = tid >> 2, part = tid & 3;
    int sjl = srow >> 1, sb = srow & 1;        // K: row = jl*2+b
    int vb_ = srow >> 5, vd = srow & 31;       // V: row = b*32+d

    for (int jb = jb0; jb < jbe; ++jb) {
        int j0 = jb * 32;
        __syncthreads();
        {   // coalesced staging: each thread one 16B K piece + one 16B V piece
            s16x8 kv = *(const s16x8*)(kb + (size_t)(j0 + sjl) * 512 + sb * 256 + hb + part * 8);
            *(s16x8*)&ks[sb][sjl][part * 8] = kv;
            s16x8 vv = *(const s16x8*)(vt + (size_t)(vb_ * 256 + hb + vd) * 1600 + j0 + part * 8);
            *(s16x8*)&vs[vb_][vd][part * 8] = vv;
        }
        __syncthreads();

        s16x8 kf00 = *(const s16x8*)&ks[0][c][qd * 8];        // b0, js0
        s16x8 kf10 = *(const s16x8*)&ks[1][c][qd * 8];        // b1, js0
        s16x8 kf01 = *(const s16x8*)&ks[0][16 + c][qd * 8];   // b0, js1
        s16x8 kf11 = *(const s16x8*)&ks[1][16 + c][qd * 8];   // b1, js1

        f32x4 z4 = {};
        f32x4 sd0 = __builtin_amdgcn_mfma_f32_16x16x32_bf16(qf0, kf00, z4, 0, 0, 0);
        sd0       = __builtin_amdgcn_mfma_f32_16x16x32_bf16(qf1, kf10, sd0, 0, 0, 0);
        f32x4 sd1 = __builtin_amdgcn_mfma_f32_16x16x32_bf16(qf0, kf01, z4, 0, 0, 0);
        sd1       = __builtin_amdgcn_mfma_f32_16x16x32_bf16(qf1, kf11, sd1, 0, 0, 0);
#pragma unroll
        for (int r = 0; r < 4; ++r) {
            float e0v = __expf(sd0[r] * 0.17677669529663687f);
            At[w][4 * qd + r][c]      = f2bf(__builtin_amdgcn_rcpf(1.f + e0v));
            float e1v = __expf(sd1[r] * 0.17677669529663687f);
            At[w][4 * qd + r][16 + c] = f2bf(__builtin_amdgcn_rcpf(1.f + e1v));
        }
        asm volatile("s_waitcnt lgkmcnt(0)" ::: "memory");
        s16x8 af = *(const s16x8*)&At[w][c][qd * 8];

        s16x8 vf00 = *(const s16x8*)&vs[0][c][qd * 8];        // b0, dh0
        s16x8 vf01 = *(const s16x8*)&vs[0][16 + c][qd * 8];   // b0, dh1
        s16x8 vf10 = *(const s16x8*)&vs[1][c][qd * 8];        // b1, dh0
        s16x8 vf11 = *(const s16x8*)&vs[1][16 + c][qd * 8];   // b1, dh1

        o0[0] = __builtin_amdgcn_mfma_f32_16x16x32_bf16(af, vf00, o0[0], 0, 0, 0);
        o0[1] = __builtin_amdgcn_mfma_f32_16x16x32_bf16(af, vf01, o0[1], 0, 0, 0);
        t1[0] = __builtin_amdgcn_mfma_f32_16x16x32_bf16(af, vf10, t1[0], 0, 0, 0);
        t1[1] = __builtin_amdgcn_mfma_f32_16x16x32_bf16(af, vf11, t1[1], 0, 0, 0);
    }

    // partial store (each (q4,i,e) written exactly once)
    size_t base = (size_t)q4 * 409600;
#pragma unroll
    for (int dh = 0; dh < 2; ++dh)
#pragma unroll
        for (int r = 0; r < 4; ++r) {
            size_t idx = base + (size_t)(i0 + 4 * qd + r) * 256 + hb + dh * 16 + c;
            pO[idx] = o0[dh][r];
            pT[idx] = t1[dh][r];
        }
}

// ---------------------------------------------------------------------------
// Combine 4 j-quarter partials: out[i][0][e] = sum pO; out[i][1][e] = sumv1-sum pT
// ---------------------------------------------------------------------------
__global__ __launch_bounds__(256) void lgat_combine(const float* __restrict__ pO,
                                                    const float* __restrict__ pT,
                                                    const float* __restrict__ sumv1,
                                                    u16* __restrict__ out) {
    int t = blockIdx.x * 256 + threadIdx.x;    // 409600
    int e = t & 255;
    int i = t >> 8;
    float o  = pO[t] + pO[t + 409600] + pO[t + 819200] + pO[t + 1228800];
    float tt = pT[t] + pT[t + 409600] + pT[t + 819200] + pT[t + 1228800];
    out[(size_t)i * 512 + e]       = (u16)f2bf(o);
    out[(size_t)i * 512 + 256 + e] = (u16)f2bf(sumv1[e] - tt);
}

// ---------------------------------------------------------------------------
// Cross attention, MFMA. q [1600][2][256] bf16; k [100][2][256] bf16;
// vt [2][256][128] bf16 zero-padded. Softmax over 100 keys (pad masked).
// ---------------------------------------------------------------------------
__global__ __launch_bounds__(64) void cross_attn_mfma(
    const u16* __restrict__ qb, const u16* __restrict__ kb,
    const u16* __restrict__ vt, u16* __restrict__ out)
{
    __shared__ short At[16][136];
    int lane = threadIdx.x;
    int c  = lane & 15;
    int qd = lane >> 4;
    int bx = blockIdx.x;
    int it = bx % 100;
    int hb2 = bx / 100;
    int h = hb2 >> 1, b = hb2 & 1;
    int i0 = it * 16;
    int hb = h * 32;

    for (int z = lane; z < 16 * 24; z += 64)
        At[z / 24][112 + (z % 24)] = 0;

    const u16* qp = qb + ((size_t)(i0 + c) * 2 + b) * 256 + hb + qd * 8;
    s16x8 qf = *(const s16x8*)qp;

    f32x4 s[7];
#pragma unroll
    for (int jt = 0; jt < 7; ++jt) {
        int j = jt * 16 + c;
        s16x8 kf = {};
        if (j < NGLO) kf = *(const s16x8*)(kb + ((size_t)j * 2 + b) * 256 + hb + qd * 8);
        f32x4 z4 = {};
        s[jt] = __builtin_amdgcn_mfma_f32_16x16x32_bf16(qf, kf, z4, 0, 0, 0);
    }
    if (c >= 4) {
#pragma unroll
        for (int r = 0; r < 4; ++r) s[6][r] = -1e30f;
    }
#pragma unroll
    for (int jt = 0; jt < 7; ++jt)
#pragma unroll
        for (int r = 0; r < 4; ++r) s[jt][r] *= 0.17677669529663687f;

    float l[4];
#pragma unroll
    for (int r = 0; r < 4; ++r) {
        float mm = s[0][r];
#pragma unroll
        for (int jt = 1; jt < 7; ++jt) mm = fmaxf(mm, s[jt][r]);
        mm = fmaxf(mm, __shfl_xor(mm, 1));
        mm = fmaxf(mm, __shfl_xor(mm, 2));
        mm = fmaxf(mm, __shfl_xor(mm, 4));
        mm = fmaxf(mm, __shfl_xor(mm, 8));
        float ll = 0.f;
#pragma unroll
        for (int jt = 0; jt < 7; ++jt) {
            float p = __expf(s[jt][r] - mm);
            s[jt][r] = p;
            ll += p;
        }
        ll += __shfl_xor(ll, 1);
        ll += __shfl_xor(ll, 2);
        ll += __shfl_xor(ll, 4);
        ll += __shfl_xor(ll, 8);
        l[r] = ll;
    }
#pragma unroll
    for (int jt = 0; jt < 7; ++jt)
#pragma unroll
        for (int r = 0; r < 4; ++r)
            At[4 * qd + r][jt * 16 + c] = f2bf(s[jt][r]);
    asm volatile("s_waitcnt lgkmcnt(0)" ::: "memory");

    f32x4 o[2] = {};
#pragma unroll
    for (int kc = 0; kc < 4; ++kc) {
        s16x8 af = *(const s16x8*)&At[c][kc * 32 + qd * 8];
#pragma unroll
        for (int dh = 0; dh < 2; ++dh) {
            s16x8 vf = *(const s16x8*)(vt + (size_t)(b * 256 + hb + dh * 16 + c) * 128
                                       + kc * 32 + qd * 8);
            o[dh] = __builtin_amdgcn_mfma_f32_16x16x32_bf16(af, vf, o[dh], 0, 0, 0);
        }
    }
#pragma unroll
    for (int dh = 0; dh < 2; ++dh)
#pragma unroll
        for (int r = 0; r < 4; ++r) {
            int ii = i0 + 4 * qd + r;
            out[((size_t)ii * 2 + b) * 256 + hb + dh * 16 + c] = (u16)f2bf(o[dh][r] / l[r]);
        }
}

// ---------------------------------------------------------------------------
// LayerNorm over E=256 of (P + R). fp32 out + optional bf16 shadow.
// mode 0: out[r][c].  mode 1: out[b*256*1600 + c*1600 + n] (final BCHW write)
// ---------------------------------------------------------------------------
__global__ __launch_bounds__(256) void ln_kernel(const float* __restrict__ P,
                                                 const float* __restrict__ R,
                                                 const float* __restrict__ g,
                                                 const float* __restrict__ bb,
                                                 float* __restrict__ out,
                                                 u16* __restrict__ outb, int mode) {
    int r = blockIdx.x;
    int c = threadIdx.x;
    size_t o = (size_t)r * 256 + c;
    float x = P[o] + R[o];
    float s1 = x, s2 = x * x;
#pragma unroll
    for (int off = 1; off < 64; off <<= 1) {
        s1 += __shfl_xor(s1, off);
        s2 += __shfl_xor(s2, off);
    }
    __shared__ float w1[4], w2[4];
    int wid = c >> 6;
    if ((c & 63) == 0) { w1[wid] = s1; w2[wid] = s2; }
    __syncthreads();
    s1 = w1[0] + w1[1] + w1[2] + w1[3];
    s2 = w2[0] + w2[1] + w2[2] + w2[3];
    float mean = s1 * (1.f / 256.f);
    float var  = s2 * (1.f / 256.f) - mean * mean;
    float y = (x - mean) * rsqrtf(var + 1e-5f) * g[c] + bb[c];
    if (mode == 0) {
        out[o] = y;
        if (outb) outb[o] = (u16)f2bf(y);
    } else {
        int n = r >> 1, b = r & 1;
        out[((size_t)(b * 256 + c)) * 1600 + n] = y;
    }
}

// ---------------------------------------------------------------------------
extern "C" void kernel_launch(void* const* d_in, const int* in_sizes, int n_in,
                              void* d_out, int out_size, void* d_ws, size_t ws_size,
                              hipStream_t stream) {
    const float* x        = (const float*)d_in[0];
    const float* gat_W    = (const float*)d_in[1];  // [2][4][256][256]
    const float* gat_b    = (const float*)d_in[2];  // [2][4][256]
    // d_in[3] = gat_rel: cancels in the batch-axis softmax -> unused
    const float* cross_W  = (const float*)d_in[4];  // [4][256][256]
    const float* cross_b  = (const float*)d_in[5];  // [4][256]
    const float* ln_g     = (const float*)d_in[6];  // [3][256]
    const float* ln_b     = (const float*)d_in[7];  // [3][256]
    float* out = (float*)d_out;

    float* ws    = (float*)d_ws;
    float* nodes = ws;                      // [1600][2][256] f32
    float* lout  = nodes + 819200;          // local GAT output f32
    float* proj  = lout  + 819200;          // l_proj -> c_proj f32
    float* gn    = proj  + 819200;          // [100][2][256] f32
    float* gprj  = gn    + 51200;
    float* gout  = gprj  + 51200;
    float* sv1l  = gout  + 51200;           // [256]
    float* sv1g  = sv1l  + 256;             // [256]
    float* pT    = sv1g  + 256;             // [4][1600][256] f32 partial T
    float* pO    = lout;                    // alias: lout+proj dead during attn
    u16* wgatb  = (u16*)(pT + 1638400);     // 2*4*65536 bf16 weights
    u16* wcrsb  = wgatb + 524288;           // 4*65536
    u16* nodesb = wcrsb + 262144;           // [1600][2][256] bf16
    u16* qbuf   = nodesb + 819200;
    u16* kbuf   = qbuf + 819200;            // local K; later reused as cattb
    u16* vbuf   = kbuf + 819200;            // local V; later reused as loutb
    u16* vtb    = vbuf + 819200;            // [2][256][1600]
    u16* attb   = vtb + 819200;             // l_att; later reused as cqb
    u16* gnb    = attb + 819200;            // [100][2][256]
    u16* gqb    = gnb + 51200;              // gqb/gkb/gvb contiguous (batched z)
    u16* gkb    = gqb + 51200;
    u16* gvb    = gkb + 51200;
    u16* gvt    = gvb + 51200;              // [2][256][128]
    u16* gattb  = gvt + 65536;
    u16* goutb  = gattb + 51200;
    u16* ckb    = goutb + 51200;            // ckb/cvb contiguous (batched z)
    u16* cvb    = ckb + 51200;
    u16* cvt    = cvb + 51200;              // [2][256][128]
    u16* loutb  = vbuf;                     // reuse (V consumed by vtrans)
    u16* cqb    = attb;                     // reuse (att consumed by proj gemm)
    u16* cattb  = kbuf;                     // reuse (K consumed by lgat_attn)

    const u16* W0b = wgatb;                 // global GAT weights bf16
    const u16* W1b = wgatb + 4 * 65536;     // local GAT weights bf16
    const float* b0 = gat_b;
    const float* b1 = gat_b + 4 * 256;

    wconv_kernel<<<768, 256, 0, stream>>>(gat_W, cross_W, wgatb, wcrsb);
    prep_kernel<<<3400, 256, 0, stream>>>(x, nodes, nodesb, gn, gnb);

    // ---- global GAT ----
    gemm_mfma<true><<<dim3(7, 4, 3), 64, 0, stream>>>(gnb, W0b, b0, gqb, 200);
    vtrans_kernel<<<dim3(8, 8), 256, 0, stream>>>(gvb, gvt, 200, 128);
    colsum_kernel<<<256, 64, 0, stream>>>(gvt, sv1g, 128);
    gat_attn_mfma<<<8 * 7, 64, 0, stream>>>(gqb, gkb, gvt, sv1g, gattb, NGLO, 128, 7);
    gemm_mfma<false><<<dim3(7, 4, 1), 64, 0, stream>>>(gattb, W0b + 3 * 65536, b0 + 768, gprj, 200);
    ln_kernel<<<200, 256, 0, stream>>>(gprj, gn, ln_g, ln_b, gout, goutb, 0);

    // ---- local GAT ----
    gemm_mfma<true><<<dim3(100, 4, 3), 64, 0, stream>>>(nodesb, W1b, b1, qbuf, 3200);
    vtrans_kernel<<<dim3(100, 8), 256, 0, stream>>>(vbuf, vtb, 3200, 1600);
    colsum_kernel<<<256, 64, 0, stream>>>(vtb, sv1l, 1600);
    lgat_attn<<<800, 256, 0, stream>>>(qbuf, kbuf, vtb, pO, pT);
    lgat_combine<<<1600, 256, 0, stream>>>(pO, pT, sv1l, attb);
    gemm_mfma<false><<<dim3(100, 4, 1), 64, 0, stream>>>(attb, W1b + 3 * 65536, b1 + 768, proj, 3200);
    ln_kernel<<<3200, 256, 0, stream>>>(proj, nodes, ln_g + 256, ln_b + 256, lout, loutb, 0);

    // ---- cross attention (keys collapse to the 100 pooled nodes) ----
    gemm_mfma<true><<<dim3(100, 4, 1), 64, 0, stream>>>(loutb, wcrsb, cross_b, cqb, 3200);
    gemm_mfma<true><<<dim3(7, 4, 2), 64, 0, stream>>>(goutb, wcrsb + 1 * 65536, cross_b + 256, ckb, 200);
    vtrans_kernel<<<dim3(8, 8), 256, 0, stream>>>(cvb, cvt, 200, 128);
    cross_attn_mfma<<<1600, 64, 0, stream>>>(cqb, ckb, cvt, cattb);
    gemm_mfma<false><<<dim3(100, 4, 1), 64, 0, stream>>>(cattb, wcrsb + 3 * 65536, cross_b + 768, proj, 3200);
    ln_kernel<<<3200, 256, 0, stream>>>(proj, lout, ln_g + 512, ln_b + 512, out, (u16*)0, 1);
}